// Round 2
// baseline (10302.821 us; speedup 1.0000x reference)
//
#include <hip/hip_runtime.h>

#define BB   8
#define TT   16
#define NPIX 784
#define WIDE 28
#define PW   30      // padded LDS row width
#define PSZ  900     // 30*30 padded plane
#define CHUNK 4      // planes staged per barrier pair

__device__ __forceinline__ float sigm_(float x) { return 1.0f / (1.0f + __expf(-x)); }
__device__ __forceinline__ float tanh_(float x) { return 2.0f / (1.0f + __expf(-2.0f * x)) - 1.0f; }

// Stage weights for output channel hc as [cin][tap][gate] so one b128 read
// yields all 4 gate weights for a tap.
template<int CX, int HC>
__device__ __forceinline__ void load_weights(float* wlds, int hc, int tid,
                                             const float* __restrict__ Wx,
                                             const float* __restrict__ Wh)
{
    constexpr int CINT = CX + HC;
    for (int idx = tid; idx < CINT * 36; idx += 256) {
        int cin = idx / 36;
        int r   = idx - cin * 36;
        int ky  = r / 12;
        int r2  = r - ky * 12;
        int kx  = r2 >> 2;
        int g   = r2 & 3;
        int ch  = g * HC + hc;
        float w;
        if (CX > 0 && cin < CX) w = Wx[((long)ch * CX + cin) * 9 + ky * 3 + kx];
        else                    w = Wh[((long)ch * HC + (cin - CX)) * 9 + ky * 3 + kx];
        wlds[idx] = w;
    }
}

// Conv accumulation over CINT input planes staged through padded LDS tiles.
// acc[gate][j] += sum_cin sum_tap w * v.  py/px are unpadded coords (clamped
// to 0 for invalid j slots; results for those are never stored).
template<int CX, int HC>
__device__ __forceinline__ void conv_accum(const float* __restrict__ xb,
                                           const float* __restrict__ hb,
                                           const float* __restrict__ wlds,
                                           float* __restrict__ plds,
                                           int tid, const int* py, const int* px,
                                           float acc[4][4])
{
    constexpr int CINT = CX + HC;
    for (int c0 = 0; c0 < CINT; c0 += CHUNK) {
        __syncthreads();   // previous chunk's compute (and initial zero) done
#pragma unroll
        for (int q = 0; q < CHUNK; ++q) {
            const int cin = c0 + q;
            const float* src = (CX > 0 && cin < CX) ? (xb + (long)cin * NPIX)
                                                    : (hb + (long)(cin - CX) * NPIX);
#pragma unroll
            for (int k = 0; k < 4; ++k) {
                int i = tid + k * 256;
                if (i < NPIX) {
                    int r = i / WIDE, c = i - r * WIDE;
                    plds[q * PSZ + (r + 1) * PW + (c + 1)] = src[i];
                }
            }
        }
        __syncthreads();
#pragma unroll
        for (int q = 0; q < CHUNK; ++q) {
            const float* wrow = &wlds[(c0 + q) * 36];
            float4 w[9];
#pragma unroll
            for (int tp = 0; tp < 9; ++tp) w[tp] = *(const float4*)(wrow + tp * 4);
#pragma unroll
            for (int j = 0; j < 4; ++j) {
                const float* rp = &plds[q * PSZ + py[j] * PW + px[j]];
#pragma unroll
                for (int ky = 0; ky < 3; ++ky) {
                    float v0 = rp[ky * PW + 0];
                    float v1 = rp[ky * PW + 1];
                    float v2 = rp[ky * PW + 2];
                    float4 w0 = w[ky * 3 + 0], w1 = w[ky * 3 + 1], w2 = w[ky * 3 + 2];
                    acc[0][j] = fmaf(v2, w2.x, fmaf(v1, w1.x, fmaf(v0, w0.x, acc[0][j])));
                    acc[1][j] = fmaf(v2, w2.y, fmaf(v1, w1.y, fmaf(v0, w0.y, acc[1][j])));
                    acc[2][j] = fmaf(v2, w2.z, fmaf(v1, w1.z, fmaf(v0, w0.z, acc[2][j])));
                    acc[3][j] = fmaf(v2, w2.w, fmaf(v1, w1.w, fmaf(v0, w0.w, acc[3][j])));
                }
            }
        }
    }
}

template<int CX, int HC, bool WRITE_OUT, bool USE_PRE>
__global__ __launch_bounds__(256, 3)
void cell_kernel(const float* __restrict__ xin, long xbstride,
                 const float* __restrict__ gpre, long gbstride,
                 const float* __restrict__ hin,
                 float* __restrict__ hout,
                 float* __restrict__ cbuf,
                 const float* __restrict__ Wx,
                 const float* __restrict__ bxp,
                 const float* __restrict__ Wh,
                 const float* __restrict__ Wp,
                 float* __restrict__ out2, long obstride)
{
    constexpr int CINT = CX + HC;
    __shared__ __align__(16) float wlds[CINT * 36];
    __shared__ __align__(16) float plds[CHUNK * PSZ];
    const int hc  = blockIdx.x;
    const int b   = blockIdx.y;
    const int tid = threadIdx.x;

    load_weights<CX, HC>(wlds, hc, tid, Wx, Wh);
    for (int i = tid; i < CHUNK * PSZ; i += 256) plds[i] = 0.0f;  // halo zeros

    int py[4], px[4];
    bool pv[4];
#pragma unroll
    for (int j = 0; j < 4; ++j) {
        int p = tid + j * 256;
        pv[j] = (p < NPIX);
        if (!pv[j]) p = 0;          // clamp: LDS reads stay in-bounds, result unused
        int y = p / WIDE;
        px[j] = p - y * WIDE;
        py[j] = y;
    }

    float acc[4][4];
#pragma unroll
    for (int g = 0; g < 4; ++g)
#pragma unroll
        for (int j = 0; j < 4; ++j) acc[g][j] = 0.0f;

    if (USE_PRE) {
        const float* gb = gpre + (long)b * gbstride;
#pragma unroll
        for (int g = 0; g < 4; ++g) {
            const float* gp = gb + (long)(g * HC + hc) * NPIX;
#pragma unroll
            for (int j = 0; j < 4; ++j) {
                int p = tid + j * 256;
                if (pv[j]) acc[g][j] = gp[p];
            }
        }
    }

    const float* xb = (CX > 0) ? (xin + (long)b * xbstride) : nullptr;
    const float* hb = hin + (long)b * HC * NPIX;
    conv_accum<CX, HC>(xb, hb, wlds, plds, tid, py, px, acc);

    const float bi = bxp[0 * HC + hc];
    const float bf = bxp[1 * HC + hc];
    const float bg = bxp[2 * HC + hc];
    const float bo = bxp[3 * HC + hc];
    float* crow = cbuf + ((long)b * HC + hc) * NPIX;
    float* hrow = hout + ((long)b * HC + hc) * NPIX;
    const float* pip = Wp + (long)(0 * HC + hc) * NPIX;
    const float* pfp = Wp + (long)(1 * HC + hc) * NPIX;
    const float* pop = Wp + (long)(2 * HC + hc) * NPIX;

#pragma unroll
    for (int j = 0; j < 4; ++j) {
        if (!pv[j]) continue;
        int p = tid + j * 256;
        float cprev = crow[p];
        float ig = sigm_(acc[0][j] + bi + cprev * pip[p]);
        float fg = sigm_(acc[1][j] + bf + cprev * pfp[p]);
        float gg = tanh_(acc[2][j] + bg);
        float cn = fg * cprev + ig * gg;
        float og = sigm_(acc[3][j] + bo + cn * pop[p]);
        float hn = og * tanh_(cn);
        crow[p] = cn;
        hrow[p] = hn;
        if (WRITE_OUT) out2[(long)b * obstride + (long)hc * NPIX + p] = hn;
    }
}

// Time-parallel precompute of gx0 = conv(x, Wx0) (no bias) over all B*T images.
template<int CX, int HC>
__global__ __launch_bounds__(256, 3)
void conv_pre_kernel(const float* __restrict__ x,   // (B*T, CX, 784)
                     const float* __restrict__ Wx,  // (4HC, CX, 3, 3)
                     float* __restrict__ gout)      // (B*T, 4HC, 784)
{
    __shared__ __align__(16) float wlds[CX * 36];
    __shared__ __align__(16) float plds[CHUNK * PSZ];
    const int hc  = blockIdx.x;
    const int bt  = blockIdx.y;
    const int tid = threadIdx.x;

    load_weights<CX, 0>(wlds, hc * 0, tid, Wx, nullptr);  // dummy; specialized below
    // NOTE: load_weights<CX,0> would index Wh; do the conv_pre weight layout here:
    for (int idx = tid; idx < CX * 36; idx += 256) {
        int cin = idx / 36;
        int r   = idx - cin * 36;
        int ky  = r / 12;
        int r2  = r - ky * 12;
        int kx  = r2 >> 2;
        int g   = r2 & 3;
        wlds[idx] = Wx[((long)(g * HC + hc) * CX + cin) * 9 + ky * 3 + kx];
    }
    for (int i = tid; i < CHUNK * PSZ; i += 256) plds[i] = 0.0f;

    int py[4], px[4];
    bool pv[4];
#pragma unroll
    for (int j = 0; j < 4; ++j) {
        int p = tid + j * 256;
        pv[j] = (p < NPIX);
        if (!pv[j]) p = 0;
        int y = p / WIDE;
        px[j] = p - y * WIDE;
        py[j] = y;
    }

    float acc[4][4];
#pragma unroll
    for (int g = 0; g < 4; ++g)
#pragma unroll
        for (int j = 0; j < 4; ++j) acc[g][j] = 0.0f;

    const float* xb = x + (long)bt * CX * NPIX;
    conv_accum<CX, 0>(xb, nullptr, wlds, plds, tid, py, px, acc);

#pragma unroll
    for (int g = 0; g < 4; ++g) {
        float* gp = gout + ((long)bt * 4 * HC + (long)g * HC + hc) * NPIX;
#pragma unroll
        for (int j = 0; j < 4; ++j) {
            int p = tid + j * 256;
            if (pv[j]) gp[p] = acc[g][j];
        }
    }
}

extern "C" void kernel_launch(void* const* d_in, const int* in_sizes, int n_in,
                              void* d_out, int out_size, void* d_ws, size_t ws_size,
                              hipStream_t stream)
{
    const float* x   = (const float*)d_in[0];
    const float* Wx0 = (const float*)d_in[1];
    const float* bx0 = (const float*)d_in[2];
    const float* Wh0 = (const float*)d_in[3];
    const float* Wp0 = (const float*)d_in[4];
    const float* Wx1 = (const float*)d_in[5];
    const float* bx1 = (const float*)d_in[6];
    const float* Wh1 = (const float*)d_in[7];
    const float* Wp1 = (const float*)d_in[8];
    const float* Wx2 = (const float*)d_in[9];
    const float* bx2 = (const float*)d_in[10];
    const float* Wh2 = (const float*)d_in[11];
    const float* Wp2 = (const float*)d_in[12];
    (void)in_sizes; (void)n_in; (void)out_size;

    float* out = (float*)d_out;
    float* ws  = (float*)d_ws;

    const long S64 = (long)BB * 64 * NPIX;   // 401408
    const long S32 = (long)BB * 32 * NPIX;   // 200704

    float* h0a = ws;        float* h0b = h0a + S64; float* c0 = h0b + S64;
    float* h1a = c0 + S64;  float* h1b = h1a + S32; float* c1 = h1b + S32;
    float* h2a = c1 + S32;  float* h2b = h2a + S64; float* c2 = h2b + S64;
    float* state_end = c2 + S64;
    const long state_floats = (long)(state_end - ws);           // 3,010,560
    float* gx0 = state_end;
    const long gx0_floats = (long)BB * TT * 256 * NPIX;         // 25,690,112
    const bool use_pre =
        (long)ws_size >= (state_floats + gx0_floats) * (long)sizeof(float);

    hipMemsetAsync(d_ws, 0, (size_t)state_floats * sizeof(float), stream);

    if (use_pre) {
        conv_pre_kernel<192, 64><<<dim3(64, BB * TT), 256, 0, stream>>>(x, Wx0, gx0);
    }

    float* h0[2] = { h0a, h0b };
    float* h1[2] = { h1a, h1b };
    float* h2[2] = { h2a, h2b };

    for (int t = 0; t < TT; ++t) {
        const int cur = t & 1, nxt = cur ^ 1;
        if (use_pre) {
            cell_kernel<0, 64, false, true><<<dim3(64, BB), 256, 0, stream>>>(
                nullptr, 0,
                gx0 + (long)t * 256 * NPIX, (long)TT * 256 * NPIX,
                h0[cur], h0[nxt], c0, Wx0, bx0, Wh0, Wp0, nullptr, 0);
        } else {
            cell_kernel<192, 64, false, false><<<dim3(64, BB), 256, 0, stream>>>(
                x + (long)t * 192 * NPIX, (long)TT * 192 * NPIX,
                nullptr, 0,
                h0[cur], h0[nxt], c0, Wx0, bx0, Wh0, Wp0, nullptr, 0);
        }
        cell_kernel<64, 32, false, false><<<dim3(32, BB), 256, 0, stream>>>(
            h0[nxt], (long)64 * NPIX, nullptr, 0,
            h1[cur], h1[nxt], c1, Wx1, bx1, Wh1, Wp1, nullptr, 0);
        cell_kernel<32, 64, true, false><<<dim3(64, BB), 256, 0, stream>>>(
            h1[nxt], (long)32 * NPIX, nullptr, 0,
            h2[cur], h2[nxt], c2, Wx2, bx2, Wh2, Wp2,
            out + (long)t * 64 * NPIX, (long)TT * 64 * NPIX);
    }
}

// Round 3
// 1633.402 us; speedup vs baseline: 6.3076x; 6.3076x over previous
//
#include <hip/hip_runtime.h>

typedef _Float16 f16;
typedef f16 f16x8 __attribute__((ext_vector_type(8)));
typedef float f32x4 __attribute__((ext_vector_type(4)));

#define BB 8
#define TT 16
#define NPIX 784
#define W28 28

__device__ __forceinline__ float sigm_(float x) { return 1.0f / (1.0f + __expf(-x)); }
__device__ __forceinline__ float tanh_(float x) { return 2.0f / (1.0f + __expf(-2.0f * x)) - 1.0f; }

// Implicit-GEMM 3x3 conv + (optional) fused LSTM pointwise epilogue.
// Block: 256 threads = 4 waves; computes all M=4*HC gate rows for one 4x4
// spatial tile of one batch image.  K = 9*CINT via mfma_f32_16x16x32_f16.
// MODE 0: conv_pre   (epilogue: write raw gate tile f16, tiled layout)
// MODE 1: L0 cell    (adds precomputed gx tile in epilogue)
// MODE 2: generic cell (L1 / L2)
template<int CINT, int HC, int MODE>
__global__ __launch_bounds__(256)
void cell_mfma(const f16* __restrict__ Apack,   // [4HC][9*CINT] k-contiguous
               const f16* __restrict__ in0, int split,   // ch [0,split)
               const f16* __restrict__ in1,              // ch [split,CINT)
               const f16* __restrict__ gxt, long gx_bstride, // MODE1
               f16* __restrict__ gxout,                  // MODE0
               const float* __restrict__ bx,
               const float* __restrict__ Wp,             // (3,HC,784)
               float* __restrict__ cbuf,                 // [b][pix][HC] f32
               f16* __restrict__ hout)                   // [b][pix][HC] f16
{
    constexpr int CINTP = CINT + 8;     // LDS channel pad (bank decorrelation)
    constexpr int NSUB  = HC / 16;      // 16-row m-subtiles per wave
    constexpr int MBLK  = 4 * HC;
    constexpr int KTOT  = 9 * CINT;
    __shared__ __align__(16) f16 S[36 * CINTP];
    __shared__ float C[MBLK * 17];      // +17 stride: conflict-free epilogue

    const int tile = blockIdx.x;        // 0..48 (7x7 tiles of 4x4)
    const int b    = blockIdx.y;        // batch (cells) or b*T+t (pre)
    const int tid  = threadIdx.x;
    const int Y0 = (tile / 7) * 4, X0 = (tile % 7) * 4;

    // ---- stage 6x6-halo x CINT input tile into LDS (f16, ch-contiguous) ----
    constexpr int CI8 = CINT / 8;
    for (int it = tid; it < 36 * CI8; it += 256) {
        int loc = it / CI8;
        int cc  = (it - loc * CI8) * 8;
        int ly = loc / 6, lx = loc - ly * 6;
        int y = Y0 - 1 + ly, x = X0 - 1 + lx;
        f16x8 v = {};
        if (y >= 0 && y < W28 && x >= 0 && x < W28) {
            int pix = y * W28 + x;
            const f16* src = (cc < split)
                ? in0 + ((long)b * NPIX + pix) * split + cc
                : in1 + ((long)b * NPIX + pix) * (CINT - split) + (cc - split);
            v = *(const f16x8*)src;
        }
        *(f16x8*)&S[loc * CINTP + cc] = v;
    }
    __syncthreads();

    const int lane = tid & 63, wv = tid >> 6;
    const int ln = lane & 15, quad = lane >> 4;
    const int sy = ln >> 2, sx = ln & 3;     // n -> (ty,tx) in 4x4 tile

    f32x4 acc[NSUB] = {};
    const f16* ap[NSUB];
#pragma unroll
    for (int s = 0; s < NSUB; ++s)
        ap[s] = Apack + (long)(wv * 16 * NSUB + s * 16 + ln) * KTOT + quad * 8;

#pragma unroll
    for (int tap = 0; tap < 9; ++tap) {
        const int ky = tap / 3, kx = tap - ky * 3;
        const f16* srow = &S[((sy + ky) * 6 + (sx + kx)) * CINTP + quad * 8];
        const int kbase = tap * CINT;
#pragma unroll
        for (int c0 = 0; c0 < CINT; c0 += 32) {
            f16x8 bf = *(const f16x8*)(srow + c0);          // ds_read_b128
#pragma unroll
            for (int s = 0; s < NSUB; ++s) {
                f16x8 af = *(const f16x8*)(ap[s] + kbase + c0);  // global 16B
                acc[s] = __builtin_amdgcn_mfma_f32_16x16x32_f16(af, bf, acc[s], 0, 0, 0);
            }
        }
    }

    // ---- acc -> LDS C (C/D layout: m = quad*4+r, n = ln) ----
#pragma unroll
    for (int s = 0; s < NSUB; ++s) {
        int m = wv * 16 * NSUB + s * 16 + quad * 4;
#pragma unroll
        for (int r = 0; r < 4; ++r)
            C[(m + r) * 17 + ln] = acc[s][r];
    }
    __syncthreads();

    if (MODE == 0) {
        // raw gate tile out: [tile-of-b][n*256 + m] f16, fully coalesced
        f16* dst = gxout + (long)(b * 49 + tile) * (MBLK * 16);
#pragma unroll
        for (int it = 0; it < 16; ++it) {
            int idx = it * 256 + tid;
            int m = idx & (MBLK - 1), n = idx >> 8;   // MBLK==256 for pre
            dst[n * MBLK + m] = (f16)C[m * 17 + n];
        }
    } else {
        constexpr int PER = HC * 16 / 256;
#pragma unroll
        for (int it = 0; it < PER; ++it) {
            int idx = it * 256 + tid;
            int hc = idx & (HC - 1), n = idx / HC;    // lanes -> hc contiguous
            int y = Y0 + (n >> 2), x = X0 + (n & 3);
            int pix = y * W28 + x;
            float g0 = C[(0 * HC + hc) * 17 + n] + bx[0 * HC + hc];
            float g1 = C[(1 * HC + hc) * 17 + n] + bx[1 * HC + hc];
            float g2 = C[(2 * HC + hc) * 17 + n] + bx[2 * HC + hc];
            float g3 = C[(3 * HC + hc) * 17 + n] + bx[3 * HC + hc];
            if (MODE == 1) {
                const f16* g = gxt + (long)b * gx_bstride + (long)tile * 4096 + n * 256;
                g0 += (float)g[0 * 64 + hc];
                g1 += (float)g[1 * 64 + hc];
                g2 += (float)g[2 * 64 + hc];
                g3 += (float)g[3 * 64 + hc];
            }
            long ci = ((long)b * NPIX + pix) * HC + hc;
            float cp = cbuf[ci];
            float pi = Wp[(0 * HC + hc) * NPIX + pix];
            float pf = Wp[(1 * HC + hc) * NPIX + pix];
            float po = Wp[(2 * HC + hc) * NPIX + pix];
            float ig = sigm_(g0 + cp * pi);
            float fg = sigm_(g1 + cp * pf);
            float gg = tanh_(g2);
            float cn = fg * cp + ig * gg;
            float og = sigm_(g3 + cn * po);
            float hn = og * tanh_(cn);
            cbuf[ci] = cn;
            hout[ci] = (f16)hn;
        }
    }
}

// Pack all conv weights to f16 [m][tap*CINT+cin] (k-contiguous, tap-major).
__global__ __launch_bounds__(256)
void pack_weights(const float* __restrict__ Wx0, const float* __restrict__ Wh0,
                  const float* __restrict__ Wx1, const float* __restrict__ Wh1,
                  const float* __restrict__ Wx2, const float* __restrict__ Wh2,
                  f16* __restrict__ A)
{
    const int NPRE = 256 * 1728, N0 = 256 * 576, N1 = 128 * 864, N2 = 256 * 864;
    int idx = blockIdx.x * 256 + threadIdx.x;
    if (idx >= NPRE + N0 + N1 + N2) return;
    float v;
    if (idx < NPRE) {
        int m = idx / 1728, k = idx % 1728, tap = k / 192, ci = k % 192;
        v = Wx0[(m * 192 + ci) * 9 + tap];
    } else if (idx < NPRE + N0) {
        int r = idx - NPRE; int m = r / 576, k = r % 576, tap = k / 64, ci = k % 64;
        v = Wh0[(m * 64 + ci) * 9 + tap];
    } else if (idx < NPRE + N0 + N1) {
        int r = idx - NPRE - N0; int m = r / 864, k = r % 864, tap = k / 96, ci = k % 96;
        v = (ci < 64) ? Wx1[(m * 64 + ci) * 9 + tap] : Wh1[(m * 32 + (ci - 64)) * 9 + tap];
    } else {
        int r = idx - NPRE - N0 - N1; int m = r / 864, k = r % 864, tap = k / 96, ci = k % 96;
        v = (ci < 32) ? Wx2[(m * 32 + ci) * 9 + tap] : Wh2[(m * 64 + (ci - 32)) * 9 + tap];
    }
    A[idx] = (f16)v;
}

// x (B*T,192,784) f32 -> xT (B*T,784,192) f16, LDS-bounced transpose.
__global__ __launch_bounds__(256)
void transpose_x(const float* __restrict__ x, f16* __restrict__ xT)
{
    __shared__ float T[16 * 200];
    const int bt = blockIdx.y, p0 = blockIdx.x * 16;
    const int tid = threadIdx.x;
    const float* xb = x + (long)bt * 192 * NPIX;
#pragma unroll
    for (int it = 0; it < 12; ++it) {
        int idx = it * 256 + tid;
        int c = idx >> 4, p = idx & 15;        // lanes -> p: coalesced reads
        T[p * 200 + c] = xb[c * NPIX + p0 + p];
    }
    __syncthreads();
    f16* dst = xT + ((long)bt * NPIX + p0) * 192;
#pragma unroll
    for (int it = 0; it < 12; ++it) {
        int idx = it * 256 + tid;
        int p = idx / 192, c = idx - p * 192;  // lanes -> c: coalesced writes
        dst[p * 192 + c] = (f16)T[p * 200 + c];
    }
}

// h2 history f16 [17][b][pix][64] (slot t+1) -> out f32 (B,T,64,28,28)
__global__ __launch_bounds__(256)
void reshape_out(const f16* __restrict__ h2buf, float* __restrict__ out)
{
    int idx = blockIdx.x * 256 + threadIdx.x;   // 6,422,528 total, exact grid
    int pix = idx % NPIX; int r = idx / NPIX;
    int hc = r & 63; r >>= 6;
    int t = r & 15; int b = r >> 4;
    out[idx] = (float)h2buf[((((long)(t + 1) * BB + b) * NPIX) + pix) * 64 + hc];
}

extern "C" void kernel_launch(void* const* d_in, const int* in_sizes, int n_in,
                              void* d_out, int out_size, void* d_ws, size_t ws_size,
                              hipStream_t stream)
{
    const float* x   = (const float*)d_in[0];
    const float* Wx0 = (const float*)d_in[1];
    const float* bx0 = (const float*)d_in[2];
    const float* Wh0 = (const float*)d_in[3];
    const float* Wp0 = (const float*)d_in[4];
    const float* Wx1 = (const float*)d_in[5];
    const float* bx1 = (const float*)d_in[6];
    const float* Wh1 = (const float*)d_in[7];
    const float* Wp1 = (const float*)d_in[8];
    const float* Wx2 = (const float*)d_in[9];
    const float* bx2 = (const float*)d_in[10];
    const float* Wh2 = (const float*)d_in[11];
    const float* Wp2 = (const float*)d_in[12];
    (void)in_sizes; (void)n_in; (void)out_size; (void)ws_size;

    char* w = (char*)d_ws;
    // ---- ws layout (bytes), total 111,828,992 ----
    f16* Apack = (f16*)w;                                  //  1,843,200
    f16* Apre  = Apack;
    f16* Ap0   = Apre + 256L * 1728;
    f16* Ap1   = Ap0  + 256L * 576;
    f16* Ap2   = Ap1  + 128L * 864;
    f16* xT    = (f16*)(w + 1843200);                      // 38,535,168
    f16* gx0t  = (f16*)(w + 1843200 + 38535168);           // 51,380,224
    float* c0  = (float*)(w + 1843200 + 38535168 + 51380224);
    float* c1  = c0 + (long)BB * NPIX * 64;
    float* c2  = c1 + (long)BB * NPIX * 32;
    f16* h0    = (f16*)(c2 + (long)BB * NPIX * 64);        // 2 parities x 64ch
    f16* h1    = h0 + 2L * BB * NPIX * 64;                 // 2 parities x 32ch
    f16* h2buf = h1 + 2L * BB * NPIX * 32;                 // 17 slots x 64ch

    // zero c0/c1/c2 + h0(both) + h1(both) + h2 slot0 (contiguous region)
    hipMemsetAsync(c0, 0, (size_t)(4014080 + 1605632 + 802816 + 802816), stream);

    pack_weights<<<3600, 256, 0, stream>>>(Wx0, Wh0, Wx1, Wh1, Wx2, Wh2, Apack);
    transpose_x<<<dim3(49, BB * TT), 256, 0, stream>>>(x, xT);

    // time-parallel layer-0 input conv for all B*T images
    cell_mfma<192, 64, 0><<<dim3(49, BB * TT), 256, 0, stream>>>(
        Apre, xT, 192, nullptr, nullptr, 0, gx0t,
        nullptr, nullptr, nullptr, nullptr);

    for (int t = 0; t < TT; ++t) {
        const int cur = t & 1, nxt = cur ^ 1;
        f16* h0c = h0 + (long)cur * BB * NPIX * 64;
        f16* h0n = h0 + (long)nxt * BB * NPIX * 64;
        f16* h1c = h1 + (long)cur * BB * NPIX * 32;
        f16* h1n = h1 + (long)nxt * BB * NPIX * 32;
        const f16* h2p = h2buf + (long)t * BB * NPIX * 64;
        f16* h2n = h2buf + (long)(t + 1) * BB * NPIX * 64;

        cell_mfma<64, 64, 1><<<dim3(49, BB), 256, 0, stream>>>(
            Ap0, h0c, 64, nullptr,
            gx0t + (long)t * 49 * 4096, (long)TT * 49 * 4096,
            nullptr, bx0, Wp0, c0, h0n);
        cell_mfma<96, 32, 2><<<dim3(49, BB), 256, 0, stream>>>(
            Ap1, h0n, 64, h1c, nullptr, 0, nullptr, bx1, Wp1, c1, h1n);
        cell_mfma<96, 64, 2><<<dim3(49, BB), 256, 0, stream>>>(
            Ap2, h1n, 32, h2p, nullptr, 0, nullptr, bx2, Wp2, c2, h2n);
    }

    reshape_out<<<25088, 256, 0, stream>>>(h2buf, (float*)d_out);
}